// Round 1
// baseline (61.637 us; speedup 1.0000x reference)
//
#include <hip/hip_runtime.h>

// FCOSLayer_22840636080477 — fused YOLO-style loss on MI355X.
// One kernel: per-block label staging in LDS + per-cell decode/IoU/BCE,
// block tree-reduce, one float atomicAdd per block.

constexpr int NB_   = 16;
constexpr int NA_   = 3;
constexpr int NG_   = 64;
constexpr int NCLS_ = 80;
constexpr int NK_   = 50;
constexpr int NCH_  = 85;   // 5 + NCLS
constexpr int BLOCK_ = 256;
constexpr int CELLS_ = NA_ * NG_ * NG_;     // 12288 cells per batch
constexpr int BPB_   = CELLS_ / BLOCK_;     // 48 blocks per batch

__device__ __forceinline__ float softplusf_(float x) {
    // log(1 + exp(x)), numerically stable
    return fmaxf(x, 0.0f) + log1pf(expf(-fabsf(x)));
}

__global__ __launch_bounds__(BLOCK_) void fcos_loss_kernel(
    const float* __restrict__ raw,
    const float* __restrict__ labels,
    const float* __restrict__ anchors,
    const int*   __restrict__ img_size_p,
    float*       __restrict__ out)
{
    __shared__ float s_tlx[NK_], s_tly[NK_], s_brx[NK_], s_bry[NK_], s_area[NK_];
    __shared__ float s_tgt[NK_][4];
    __shared__ int   s_valid[NK_], s_bn[NK_], s_ti[NK_], s_tj[NK_], s_tcls[NK_];
    __shared__ int   s_hasvalid;
    __shared__ float s_red[BLOCK_];

    const int tid = threadIdx.x;
    const int b   = blockIdx.x / BPB_;
    const int cid = (blockIdx.x % BPB_) * BLOCK_ + tid;
    const float img = (float)img_size_p[0];

    if (tid == 0) s_hasvalid = 0;
    __syncthreads();

    // ---- per-label preprocessing (threads 0..49) ----
    if (tid < NK_) {
        const float* lab = labels + ((size_t)b * NK_ + tid) * 5;
        float c0 = lab[0], x = lab[1], y = lab[2], w = lab[3], h = lab[4];
        bool vrow = (c0 + x + y + w + h) > 0.0f;          // labels.sum(-1) > 0
        float tx = x * NG_, ty = y * NG_;
        int ti = (int)tx, tj = (int)ty;

        // argmax IoU over all 9 anchors (wh-only IoU), first max wins
        int best = 0; float bi = -1.0f;
        #pragma unroll
        for (int n = 0; n < 9; ++n) {
            float aw = anchors[n*2]     / img;
            float ah = anchors[n*2 + 1] / img;
            float inter = fminf(w, aw) * fminf(h, ah);
            float uni   = w*h + aw*ah - inter;
            float iou   = inter / (uni + 1e-16f);
            if (iou > bi) { bi = iou; best = n; }
        }
        int bn = best % NA_;
        bool val = vrow && (best < NA_);                   // in this layer's anchor set
        if (ti < 0 || ti >= NG_ || tj < 0 || tj >= NG_) val = false;  // scatter drop

        // log-space ltrb target
        float w64 = w * NG_, h64 = h * NG_;
        float xc = floorf(tx) + 0.5f, yc = floorf(ty) + 0.5f;
        float lt = fmaxf(xc - (tx - w64*0.5f), 0.0f) * (1.0f/NG_);
        float tt = fmaxf(yc - (ty - h64*0.5f), 0.0f) * (1.0f/NG_);
        float rt = fmaxf(tx + w64*0.5f - xc, 0.0f) * (1.0f/NG_);
        float bt = fmaxf(ty + h64*0.5f - yc, 0.0f) * (1.0f/NG_);
        float awn = anchors[bn*2] / img;
        s_tgt[tid][0] = logf(lt / awn + 1e-16f);
        s_tgt[tid][1] = logf(tt / awn + 1e-16f);
        s_tgt[tid][2] = logf(rt / awn + 1e-16f);
        s_tgt[tid][3] = logf(bt / awn + 1e-16f);

        s_valid[tid] = val ? 1 : 0;
        s_bn[tid] = bn; s_ti[tid] = ti; s_tj[tid] = tj;
        s_tcls[tid] = (int)c0;
        // GT box corners in normalized units for the pred-vs-GT IoU
        s_tlx[tid] = x - w*0.5f; s_tly[tid] = y - h*0.5f;
        s_brx[tid] = x + w*0.5f; s_bry[tid] = y + h*0.5f;
        s_area[tid] = w * h;
        if (val) atomicOr(&s_hasvalid, 1);
    }
    __syncthreads();

    // ---- per-cell work ----
    const int a   = cid / (NG_*NG_);
    const int rem = cid % (NG_*NG_);
    const int j   = rem / NG_, i = rem % NG_;

    const float* cell = raw + ((size_t)(b*NA_ + a) * NCH_) * (NG_*NG_) + j*NG_ + i;
    const float r0 = cell[0*4096], r1 = cell[1*4096];
    const float r2 = cell[2*4096], r3 = cell[3*4096];
    const float cf = cell[4*4096];

    // decode pred box (normalized xywh)
    const float aw   = anchors[a*2];
    const float inv8 = 0.125f;
    float ls = expf(r0)*aw*inv8, ts = expf(r1)*aw*inv8;
    float rs = expf(r2)*aw*inv8, bs = expf(r3)*aw*inv8;
    const float scale = 8.0f / img;
    float cx = ((i + 0.5f) + (rs - ls)*0.5f) * scale;
    float cy = ((j + 0.5f) + (bs - ts)*0.5f) * scale;
    float pw = (ls + rs) * scale, ph = (ts + bs) * scale;
    float atlx = cx - pw*0.5f, atly = cy - ph*0.5f;
    float abrx = cx + pw*0.5f, abry = cy + ph*0.5f;
    float area_a = pw * ph;

    // fused: max IoU over 50 GT + cell<->label match (last k wins)
    float maxiou = -1.0f;
    int   kmatch = -1;
    for (int k = 0; k < NK_; ++k) {
        float iw = fminf(abrx, s_brx[k]) - fmaxf(atlx, s_tlx[k]);
        float ih = fminf(abry, s_bry[k]) - fmaxf(atly, s_tly[k]);
        iw = fmaxf(iw, 0.0f); ih = fmaxf(ih, 0.0f);
        float inter = iw * ih;
        float iou = inter / (area_a + s_area[k] - inter + 1e-16f);
        maxiou = fmaxf(maxiou, iou);   // invalid rows are zero boxes -> iou 0 (== ref's -1 w.r.t. >0.6)
        if (s_valid[k] && (s_bn[k] == a) && (s_tj[k] == j) && (s_ti[k] == i)) kmatch = k;
    }

    const bool gt        = (kmatch >= 0);
    const bool ignore    = (maxiou > 0.6f);
    const bool conf_mask = (s_hasvalid ? !ignore : true) || gt;

    float lsum = 0.0f;
    {   // conf BCE over all cells
        float g = gt ? 1.0f : 0.0f;
        float bce = g * softplusf_(-cf) + (1.0f - g) * softplusf_(cf);
        if (conf_mask) lsum += bce;
    }
    if (gt) {
        // bbox L2 (winner = last matching k, within scatter-duplicate tolerance)
        float d0 = r0 - s_tgt[kmatch][0];
        float d1 = r1 - s_tgt[kmatch][1];
        float d2 = r2 - s_tgt[kmatch][2];
        float d3 = r3 - s_tgt[kmatch][3];
        lsum += d0*d0 + d1*d1 + d2*d2 + d3*d3;

        // class one-hot is a UNION over colliding labels (ref scatters into class axis)
        unsigned long long m0 = 0ull, m1 = 0ull;
        for (int k = 0; k < NK_; ++k) {
            if (s_valid[k] && (s_bn[k] == a) && (s_tj[k] == j) && (s_ti[k] == i)) {
                int tc = s_tcls[k];
                if (tc >= 0 && tc < 64)       m0 |= (1ull << tc);
                else if (tc >= 64 && tc < NCLS_) m1 |= (1ull << (tc - 64));
            }
        }
        const float* cl = cell + 5*4096;
        for (int c = 0; c < NCLS_; ++c) {
            float x = cl[c*4096];
            bool on = (c < 64) ? ((m0 >> c) & 1ull) : ((m1 >> (c - 64)) & 1ull);
            lsum += on ? softplusf_(-x) : softplusf_(x);
        }
    }

    // ---- block reduction + one atomic per block ----
    s_red[tid] = lsum;
    __syncthreads();
    for (int off = BLOCK_/2; off > 0; off >>= 1) {
        if (tid < off) s_red[tid] += s_red[tid + off];
        __syncthreads();
    }
    if (tid == 0) atomicAdd(out, s_red[0]);
}

extern "C" void kernel_launch(void* const* d_in, const int* in_sizes, int n_in,
                              void* d_out, int out_size, void* d_ws, size_t ws_size,
                              hipStream_t stream) {
    const float* raw     = (const float*)d_in[0];
    const float* labels  = (const float*)d_in[1];
    const float* anchors = (const float*)d_in[2];
    const int*   img     = (const int*)d_in[3];
    float* out = (float*)d_out;

    hipMemsetAsync(out, 0, sizeof(float) * (size_t)(out_size > 0 ? out_size : 1), stream);
    fcos_loss_kernel<<<dim3(NB_ * BPB_), dim3(BLOCK_), 0, stream>>>(raw, labels, anchors, img, out);
}

// Round 2
// 25.874 us; speedup vs baseline: 2.3822x; 2.3822x over previous
//
#include <hip/hip_runtime.h>

// FCOSLayer_22840636080477 — fused YOLO-style loss on MI355X (round 2).
// Changes vs R1: wave-cooperative class BCE (kills 1-lane 80-iter straggler
// tail), float4-packed IoU loop with division eliminated, shuffle reduction.

constexpr int NB_   = 16;
constexpr int NA_   = 3;
constexpr int NG_   = 64;
constexpr int NCLS_ = 80;
constexpr int NK_   = 50;
constexpr int NCH_  = 85;   // 5 + NCLS
constexpr int BLOCK_ = 256;
constexpr int CELLS_ = NA_ * NG_ * NG_;     // 12288 cells per batch
constexpr int BPB_   = CELLS_ / BLOCK_;     // 48 blocks per batch

__device__ __forceinline__ float softplusf_(float x) {
    // log(1 + exp(x)), numerically stable
    return fmaxf(x, 0.0f) + log1pf(expf(-fabsf(x)));
}

__global__ __launch_bounds__(BLOCK_) void fcos_loss_kernel(
    const float* __restrict__ raw,
    const float* __restrict__ labels,
    const float* __restrict__ anchors,
    const int*   __restrict__ img_size_p,
    float*       __restrict__ out)
{
    __shared__ float4 s_box[NK_];            // tlx, tly, brx, bry (normalized)
    __shared__ float2 s_meta[NK_];           // x = area, y = bitcast(match code)
    __shared__ float  s_tgt[NK_][4];
    __shared__ int    s_cls[NK_];
    __shared__ int    s_hasvalid;
    __shared__ float  s_wsum[BLOCK_ / 64];

    const int tid  = threadIdx.x;
    const int lane = tid & 63;
    const int b    = blockIdx.x / BPB_;
    const int cid  = (blockIdx.x % BPB_) * BLOCK_ + tid;
    const float img = (float)img_size_p[0];

    if (tid == 0) s_hasvalid = 0;
    __syncthreads();

    // ---- per-label preprocessing (threads 0..49) ----
    if (tid < NK_) {
        const float* lab = labels + ((size_t)b * NK_ + tid) * 5;
        float c0 = lab[0], x = lab[1], y = lab[2], w = lab[3], h = lab[4];
        bool vrow = (c0 + x + y + w + h) > 0.0f;          // labels.sum(-1) > 0
        float tx = x * NG_, ty = y * NG_;
        int ti = (int)tx, tj = (int)ty;

        // argmax IoU over all 9 anchors (wh-only IoU), first max wins
        int best = 0; float bi = -1.0f;
        #pragma unroll
        for (int n = 0; n < 9; ++n) {
            float aw = anchors[n*2]     / img;
            float ah = anchors[n*2 + 1] / img;
            float inter = fminf(w, aw) * fminf(h, ah);
            float uni   = w*h + aw*ah - inter;
            float iou   = inter / (uni + 1e-16f);
            if (iou > bi) { bi = iou; best = n; }
        }
        int bn = best % NA_;
        bool val = vrow && (best < NA_);                   // in this layer's anchor set
        if (ti < 0 || ti >= NG_ || tj < 0 || tj >= NG_) val = false;  // scatter drop

        // log-space ltrb target
        float w64 = w * NG_, h64 = h * NG_;
        float xc = floorf(tx) + 0.5f, yc = floorf(ty) + 0.5f;
        float lt = fmaxf(xc - (tx - w64*0.5f), 0.0f) * (1.0f/NG_);
        float tt = fmaxf(yc - (ty - h64*0.5f), 0.0f) * (1.0f/NG_);
        float rt = fmaxf(tx + w64*0.5f - xc, 0.0f) * (1.0f/NG_);
        float bt = fmaxf(ty + h64*0.5f - yc, 0.0f) * (1.0f/NG_);
        float awn = anchors[bn*2] / img;
        s_tgt[tid][0] = logf(lt / awn + 1e-16f);
        s_tgt[tid][1] = logf(tt / awn + 1e-16f);
        s_tgt[tid][2] = logf(rt / awn + 1e-16f);
        s_tgt[tid][3] = logf(bt / awn + 1e-16f);

        s_cls[tid] = (int)c0;
        // packed match code: valid<<30 | bn<<20 | tj<<10 | ti  (invalid -> -1)
        int code = val ? ((1 << 30) | (bn << 20) | (tj << 10) | ti) : -1;
        s_meta[tid] = make_float2(w * h, __int_as_float(code));
        s_box[tid]  = make_float4(x - w*0.5f, y - h*0.5f, x + w*0.5f, y + h*0.5f);
        if (val) atomicOr(&s_hasvalid, 1);
    }
    __syncthreads();

    // ---- per-cell work ----
    const int a   = cid >> 12;            // cid / 4096
    const int rr  = cid & 4095;
    const int j   = rr >> 6, i = rr & 63;

    const float* cell = raw + (((size_t)(b*NA_ + a) * NCH_) << 12) + rr;
    const float r0 = cell[0*4096], r1 = cell[1*4096];
    const float r2 = cell[2*4096], r3 = cell[3*4096];
    const float cf = cell[4*4096];

    // decode pred box (normalized xywh -> corners)
    const float aw   = anchors[a*2];
    float ls = expf(r0)*aw*0.125f, ts = expf(r1)*aw*0.125f;
    float rs = expf(r2)*aw*0.125f, bs = expf(r3)*aw*0.125f;
    const float scale = 8.0f / img;
    float cx = ((i + 0.5f) + (rs - ls)*0.5f) * scale;
    float cy = ((j + 0.5f) + (bs - ts)*0.5f) * scale;
    float pw = (ls + rs) * scale, ph = (ts + bs) * scale;
    float atlx = cx - pw*0.5f, atly = cy - ph*0.5f;
    float abrx = cx + pw*0.5f, abry = cy + ph*0.5f;
    const float area_eps = pw * ph + 1e-16f;
    const int mycode = (1 << 30) | (a << 20) | (j << 10) | i;

    // fused: ignore test (div-free) + cell<->label match (last k wins)
    bool ign = false;
    int  kmatch = -1;
    #pragma unroll 5
    for (int k = 0; k < NK_; ++k) {
        float4 bx = s_box[k];
        float2 mt = s_meta[k];
        float iw = fminf(abrx, bx.z) - fmaxf(atlx, bx.x);
        float ih = fminf(abry, bx.w) - fmaxf(atly, bx.y);
        float inter = fmaxf(iw, 0.0f) * fmaxf(ih, 0.0f);
        // iou > 0.6  <=>  inter > 0.6*(area_a + area_k - inter + eps)
        ign |= inter > 0.6f * (area_eps + mt.x - inter);
        if (__float_as_int(mt.y) == mycode) kmatch = k;
    }

    const bool gt        = (kmatch >= 0);
    const bool conf_mask = (s_hasvalid ? !ign : true) || gt;

    float lsum = 0.0f;
    {   // conf BCE over all cells
        float bce = gt ? softplusf_(-cf) : softplusf_(cf);
        if (conf_mask) lsum += bce;
    }

    // per-gt-lane: bbox L2 + class-union mask over colliding labels
    unsigned long long m0 = 0ull, m1 = 0ull;
    if (gt) {
        float d0 = r0 - s_tgt[kmatch][0];
        float d1 = r1 - s_tgt[kmatch][1];
        float d2 = r2 - s_tgt[kmatch][2];
        float d3 = r3 - s_tgt[kmatch][3];
        lsum += d0*d0 + d1*d1 + d2*d2 + d3*d3;
        for (int k = 0; k < NK_; ++k) {
            if (__float_as_int(s_meta[k].y) == mycode) {
                int tc = s_cls[k];
                if ((unsigned)tc < 64u)          m0 |= (1ull << tc);
                else if ((unsigned)tc < (unsigned)NCLS_) m1 |= (1ull << (tc - 64));
            }
        }
    }

    // wave-cooperative class BCE: all 64 lanes split each gt cell's 80 logits
    unsigned long long gmask = __ballot(gt);
    while (gmask) {
        int L = (int)__ffsll((unsigned long long)gmask) - 1;
        gmask &= gmask - 1;
        int ccid = __shfl(cid, L);
        unsigned lo0 = __shfl((int)(unsigned)(m0 & 0xffffffffu), L);
        unsigned hi0 = __shfl((int)(unsigned)(m0 >> 32), L);
        unsigned lo1 = __shfl((int)(unsigned)(m1 & 0xffffffffu), L);
        unsigned long long mm0 = ((unsigned long long)hi0 << 32) | lo0;
        unsigned long long mm1 = (unsigned long long)lo1;

        int aa = ccid >> 12, rc = ccid & 4095;
        const float* clp = raw + (((size_t)(b*NA_ + aa) * NCH_ + 5) << 12) + rc;
        {
            float x = clp[(size_t)lane << 12];
            bool on = (mm0 >> lane) & 1ull;
            lsum += on ? softplusf_(-x) : softplusf_(x);
        }
        if (lane < NCLS_ - 64) {
            float x = clp[(size_t)(lane + 64) << 12];
            bool on = (mm1 >> lane) & 1ull;
            lsum += on ? softplusf_(-x) : softplusf_(x);
        }
    }

    // ---- wave shuffle reduce, then tiny LDS combine + one atomic ----
    #pragma unroll
    for (int off = 32; off > 0; off >>= 1) lsum += __shfl_down(lsum, off);
    if (lane == 0) s_wsum[tid >> 6] = lsum;
    __syncthreads();
    if (tid == 0) {
        float t = s_wsum[0] + s_wsum[1] + s_wsum[2] + s_wsum[3];
        atomicAdd(out, t);
    }
}

extern "C" void kernel_launch(void* const* d_in, const int* in_sizes, int n_in,
                              void* d_out, int out_size, void* d_ws, size_t ws_size,
                              hipStream_t stream) {
    const float* raw     = (const float*)d_in[0];
    const float* labels  = (const float*)d_in[1];
    const float* anchors = (const float*)d_in[2];
    const int*   img     = (const int*)d_in[3];
    float* out = (float*)d_out;

    hipMemsetAsync(out, 0, sizeof(float) * (size_t)(out_size > 0 ? out_size : 1), stream);
    fcos_loss_kernel<<<dim3(NB_ * BPB_), dim3(BLOCK_), 0, stream>>>(raw, labels, anchors, img, out);
}

// Round 3
// 24.377 us; speedup vs baseline: 2.5285x; 1.0614x over previous
//
#include <hip/hip_runtime.h>

// FCOSLayer_22840636080477 — fused YOLO-style loss on MI355X (round 3).
// vs R2: 2 cells/thread (512x192, exactly 2 blocks/CU, label LDS reads
// amortized over 2 IoU chains), div-free ignore test via pre-scaled areas,
// halved preprocessing/atomics.

constexpr int NA_   = 3;
constexpr int NG_   = 64;
constexpr int NCLS_ = 80;
constexpr int NK_   = 50;
constexpr int NCH_  = 85;    // 5 + NCLS
constexpr int BLOCK_ = 192;  // 3 waves
constexpr int GRID_  = 512;  // 2 blocks/CU exactly
constexpr int CPB_   = 384;  // cells per block (2 per thread)

__device__ __forceinline__ float softplusf_(float x) {
    return fmaxf(x, 0.0f) + log1pf(expf(-fabsf(x)));
}

__global__ __launch_bounds__(BLOCK_) void fcos_loss_kernel(
    const float* __restrict__ raw,
    const float* __restrict__ labels,
    const float* __restrict__ anchors,
    const int*   __restrict__ img_size_p,
    float*       __restrict__ out)
{
    __shared__ float4 s_box[NK_];        // tlx, tly, brx, bry (normalized)
    __shared__ float2 s_meta[NK_];       // x = 0.375*area_k, y = bitcast(code)
    __shared__ float  s_tgt[NK_][4];
    __shared__ int    s_cls[NK_];
    __shared__ int    s_hasvalid;
    __shared__ float  s_wsum[BLOCK_ / 64];

    const int tid  = threadIdx.x;
    const int lane = tid & 63;
    const int b    = blockIdx.x >> 5;           // 32 blocks per batch
    const int base = (blockIdx.x & 31) * CPB_;
    const float img = (float)img_size_p[0];

    if (tid == 0) s_hasvalid = 0;
    __syncthreads();

    // ---- per-label preprocessing (threads 0..49) ----
    if (tid < NK_) {
        const float* lab = labels + ((size_t)b * NK_ + tid) * 5;
        float c0 = lab[0], x = lab[1], y = lab[2], w = lab[3], h = lab[4];
        bool vrow = (c0 + x + y + w + h) > 0.0f;
        float tx = x * NG_, ty = y * NG_;
        int ti = (int)tx, tj = (int)ty;

        int best = 0; float bi = -1.0f;
        #pragma unroll
        for (int n = 0; n < 9; ++n) {
            float aw = anchors[n*2]     / img;
            float ah = anchors[n*2 + 1] / img;
            float inter = fminf(w, aw) * fminf(h, ah);
            float uni   = w*h + aw*ah - inter;
            float iou   = inter / (uni + 1e-16f);
            if (iou > bi) { bi = iou; best = n; }
        }
        int bn = best % NA_;
        bool val = vrow && (best < NA_);
        if (ti < 0 || ti >= NG_ || tj < 0 || tj >= NG_) val = false;

        float w64 = w * NG_, h64 = h * NG_;
        float xc = floorf(tx) + 0.5f, yc = floorf(ty) + 0.5f;
        float lt = fmaxf(xc - (tx - w64*0.5f), 0.0f) * (1.0f/NG_);
        float tt = fmaxf(yc - (ty - h64*0.5f), 0.0f) * (1.0f/NG_);
        float rt = fmaxf(tx + w64*0.5f - xc, 0.0f) * (1.0f/NG_);
        float bt = fmaxf(ty + h64*0.5f - yc, 0.0f) * (1.0f/NG_);
        float awn = anchors[bn*2] / img;
        s_tgt[tid][0] = logf(lt / awn + 1e-16f);
        s_tgt[tid][1] = logf(tt / awn + 1e-16f);
        s_tgt[tid][2] = logf(rt / awn + 1e-16f);
        s_tgt[tid][3] = logf(bt / awn + 1e-16f);

        s_cls[tid] = (int)c0;
        int code = val ? ((1 << 30) | (bn << 20) | (tj << 10) | ti) : -1;
        s_meta[tid] = make_float2(0.375f * w * h, __int_as_float(code));
        s_box[tid]  = make_float4(x - w*0.5f, y - h*0.5f, x + w*0.5f, y + h*0.5f);
        if (val) atomicOr(&s_hasvalid, 1);
    }
    __syncthreads();

    // ---- two cells per thread ----
    const int cA = base + tid;
    const int cB = cA + BLOCK_;

    // decode both cells (loads issued up-front for MLP)
    float r0A, r1A, r2A, r3A, cfA, tlxA, tlyA, brxA, bryA, t375A; int codeA;
    float r0B, r1B, r2B, r3B, cfB, tlxB, tlyB, brxB, bryB, t375B; int codeB;
    {
        int aA = cA >> 12, rrA = cA & 4095;
        int aB = cB >> 12, rrB = cB & 4095;
        const float* cellA = raw + (((size_t)(b*NA_ + aA) * NCH_) << 12) + rrA;
        const float* cellB = raw + (((size_t)(b*NA_ + aB) * NCH_) << 12) + rrB;
        r0A = cellA[0];      r0B = cellB[0];
        r1A = cellA[4096];   r1B = cellB[4096];
        r2A = cellA[2*4096]; r2B = cellB[2*4096];
        r3A = cellA[3*4096]; r3B = cellB[3*4096];
        cfA = cellA[4*4096]; cfB = cellB[4*4096];
        const float scale = 8.0f / img;

        {
            float aw = anchors[aA*2];
            float ls = expf(r0A)*aw*0.125f, ts = expf(r1A)*aw*0.125f;
            float rs = expf(r2A)*aw*0.125f, bs = expf(r3A)*aw*0.125f;
            int i = rrA & 63, j = rrA >> 6;
            float cx = ((i + 0.5f) + (rs - ls)*0.5f) * scale;
            float cy = ((j + 0.5f) + (bs - ts)*0.5f) * scale;
            float pw = (ls + rs) * scale, ph = (ts + bs) * scale;
            tlxA = cx - pw*0.5f; tlyA = cy - ph*0.5f;
            brxA = cx + pw*0.5f; bryA = cy + ph*0.5f;
            t375A = 0.375f * (pw * ph + 1e-16f);
            codeA = (1 << 30) | (aA << 20) | (j << 10) | i;
        }
        {
            float aw = anchors[aB*2];
            float ls = expf(r0B)*aw*0.125f, ts = expf(r1B)*aw*0.125f;
            float rs = expf(r2B)*aw*0.125f, bs = expf(r3B)*aw*0.125f;
            int i = rrB & 63, j = rrB >> 6;
            float cx = ((i + 0.5f) + (rs - ls)*0.5f) * scale;
            float cy = ((j + 0.5f) + (bs - ts)*0.5f) * scale;
            float pw = (ls + rs) * scale, ph = (ts + bs) * scale;
            tlxB = cx - pw*0.5f; tlyB = cy - ph*0.5f;
            brxB = cx + pw*0.5f; bryB = cy + ph*0.5f;
            t375B = 0.375f * (pw * ph + 1e-16f);
            codeB = (1 << 30) | (aB << 20) | (j << 10) | i;
        }
    }

    // fused label loop: each LDS read feeds both cells' IoU/match chains.
    bool ignA = false, ignB = false;
    int  kmA = -1, kmB = -1;
    #pragma unroll 5
    for (int k = 0; k < NK_; ++k) {
        float4 bx = s_box[k];
        float2 mt = s_meta[k];
        int    ck = __float_as_int(mt.y);
        {
            float iw = fminf(brxA, bx.z) - fmaxf(tlxA, bx.x);
            float ih = fminf(bryA, bx.w) - fmaxf(tlyA, bx.y);
            float inter = fmaxf(iw, 0.0f) * fmaxf(ih, 0.0f);
            ignA |= inter > (t375A + mt.x);     // iou > 0.6, div-free
            if (ck == codeA) kmA = k;
        }
        {
            float iw = fminf(brxB, bx.z) - fmaxf(tlxB, bx.x);
            float ih = fminf(bryB, bx.w) - fmaxf(tlyB, bx.y);
            float inter = fmaxf(iw, 0.0f) * fmaxf(ih, 0.0f);
            ignB |= inter > (t375B + mt.x);
            if (ck == codeB) kmB = k;
        }
    }

    float lsum = 0.0f;

    // wave-cooperative class BCE helper
    auto wave_cls = [&](int cid, bool gt, unsigned long long m0, unsigned long long m1) -> float {
        float acc = 0.0f;
        unsigned long long g = __ballot(gt);
        while (g) {
            int L = (int)__ffsll(g) - 1;
            g &= g - 1;
            int ccid = __shfl(cid, L);
            unsigned lo0 = (unsigned)__shfl((int)(unsigned)(m0 & 0xffffffffu), L);
            unsigned hi0 = (unsigned)__shfl((int)(unsigned)(m0 >> 32), L);
            unsigned lo1 = (unsigned)__shfl((int)(unsigned)(m1 & 0xffffffffu), L);
            unsigned long long mm0 = ((unsigned long long)hi0 << 32) | lo0;
            int aa = ccid >> 12, rc = ccid & 4095;
            const float* clp = raw + (((size_t)(b*NA_ + aa) * NCH_ + 5) << 12) + rc;
            float x = clp[(size_t)lane << 12];
            acc += ((mm0 >> lane) & 1ull) ? softplusf_(-x) : softplusf_(x);
            if (lane < NCLS_ - 64) {
                float y = clp[(size_t)(lane + 64) << 12];
                acc += ((lo1 >> lane) & 1u) ? softplusf_(-y) : softplusf_(y);
            }
        }
        return acc;
    };

    // ---- cell A epilogue ----
    {
        bool gt = (kmA >= 0);
        bool cm = (s_hasvalid ? !ignA : true) || gt;
        if (cm) lsum += gt ? softplusf_(-cfA) : softplusf_(cfA);
        unsigned long long m0 = 0ull, m1 = 0ull;
        if (gt) {
            float d0 = r0A - s_tgt[kmA][0], d1 = r1A - s_tgt[kmA][1];
            float d2 = r2A - s_tgt[kmA][2], d3 = r3A - s_tgt[kmA][3];
            lsum += d0*d0 + d1*d1 + d2*d2 + d3*d3;
            for (int k = 0; k < NK_; ++k) {
                if (__float_as_int(s_meta[k].y) == codeA) {
                    int tc = s_cls[k];
                    if ((unsigned)tc < 64u) m0 |= (1ull << tc);
                    else if ((unsigned)tc < (unsigned)NCLS_) m1 |= (1ull << (tc - 64));
                }
            }
        }
        lsum += wave_cls(cA, gt, m0, m1);
    }
    // ---- cell B epilogue ----
    {
        bool gt = (kmB >= 0);
        bool cm = (s_hasvalid ? !ignB : true) || gt;
        if (cm) lsum += gt ? softplusf_(-cfB) : softplusf_(cfB);
        unsigned long long m0 = 0ull, m1 = 0ull;
        if (gt) {
            float d0 = r0B - s_tgt[kmB][0], d1 = r1B - s_tgt[kmB][1];
            float d2 = r2B - s_tgt[kmB][2], d3 = r3B - s_tgt[kmB][3];
            lsum += d0*d0 + d1*d1 + d2*d2 + d3*d3;
            for (int k = 0; k < NK_; ++k) {
                if (__float_as_int(s_meta[k].y) == codeB) {
                    int tc = s_cls[k];
                    if ((unsigned)tc < 64u) m0 |= (1ull << tc);
                    else if ((unsigned)tc < (unsigned)NCLS_) m1 |= (1ull << (tc - 64));
                }
            }
        }
        lsum += wave_cls(cB, gt, m0, m1);
    }

    // ---- wave shuffle reduce, tiny LDS combine, one atomic per block ----
    #pragma unroll
    for (int off = 32; off > 0; off >>= 1) lsum += __shfl_down(lsum, off);
    if (lane == 0) s_wsum[tid >> 6] = lsum;
    __syncthreads();
    if (tid == 0) {
        atomicAdd(out, s_wsum[0] + s_wsum[1] + s_wsum[2]);
    }
}

extern "C" void kernel_launch(void* const* d_in, const int* in_sizes, int n_in,
                              void* d_out, int out_size, void* d_ws, size_t ws_size,
                              hipStream_t stream) {
    const float* raw     = (const float*)d_in[0];
    const float* labels  = (const float*)d_in[1];
    const float* anchors = (const float*)d_in[2];
    const int*   img     = (const int*)d_in[3];
    float* out = (float*)d_out;

    hipMemsetAsync(out, 0, sizeof(float) * (size_t)(out_size > 0 ? out_size : 1), stream);
    fcos_loss_kernel<<<dim3(GRID_), dim3(BLOCK_), 0, stream>>>(raw, labels, anchors, img, out);
}

// Round 4
// 21.343 us; speedup vs baseline: 2.8880x; 1.1422x over previous
//
#include <hip/hip_runtime.h>

// FCOSLayer_22840636080477 — fused YOLO-style loss on MI355X (round 4).
// vs R3: single dispatch (no memset node) — blocks publish partials+release
// flags in d_ws, block GRID-1 spin-reduces and stores out[0] directly;
// global channel loads issued BEFORE label preprocessing; ballot hasvalid.

constexpr int NA_   = 3;
constexpr int NG_   = 64;
constexpr int NCLS_ = 80;
constexpr int NK_   = 50;
constexpr int NCH_  = 85;    // 5 + NCLS
constexpr int BLOCK_ = 192;  // 3 waves
constexpr int GRID_  = 512;
constexpr int CPB_   = 384;  // cells per block (2 per thread)
constexpr unsigned MAGIC_ = 0x5A17C0DEu;

__device__ __forceinline__ float softplusf_(float x) {
    return fmaxf(x, 0.0f) + log1pf(expf(-fabsf(x)));
}

__global__ __launch_bounds__(BLOCK_) void fcos_loss_kernel(
    const float* __restrict__ raw,
    const float* __restrict__ labels,
    const float* __restrict__ anchors,
    const int*   __restrict__ img_size_p,
    float*       __restrict__ out,
    float*       __restrict__ partials,
    unsigned*    __restrict__ flags)
{
    __shared__ float4 s_box[NK_];        // tlx, tly, brx, bry (normalized)
    __shared__ float2 s_meta[NK_];       // x = 0.375*area_k, y = bitcast(code)
    __shared__ float  s_tgt[NK_][4];
    __shared__ int    s_cls[NK_];
    __shared__ int    s_hasvalid;
    __shared__ float  s_wsum[BLOCK_ / 64];

    const int tid  = threadIdx.x;
    const int lane = tid & 63;
    const int bid  = blockIdx.x;
    const int b    = bid >> 5;                  // 32 blocks per batch
    const int base = (bid & 31) * CPB_;
    const float img = (float)img_size_p[0];
    const float inv_img = 1.0f / img;

    // ---- issue all global channel loads FIRST (hide latency under preproc) ----
    const int cA = base + tid;
    const int cB = cA + BLOCK_;
    const int aA = cA >> 12, rrA = cA & 4095;
    const int aB = cB >> 12, rrB = cB & 4095;
    const float* cellA = raw + (((size_t)(b*NA_ + aA) * NCH_) << 12) + rrA;
    const float* cellB = raw + (((size_t)(b*NA_ + aB) * NCH_) << 12) + rrB;
    const float r0A = cellA[0];        const float r0B = cellB[0];
    const float r1A = cellA[4096];     const float r1B = cellB[4096];
    const float r2A = cellA[2*4096];   const float r2B = cellB[2*4096];
    const float r3A = cellA[3*4096];   const float r3B = cellB[3*4096];
    const float cfA = cellA[4*4096];   const float cfB = cellB[4*4096];

    // ---- per-label preprocessing (lanes 0..49 of wave 0) ----
    bool val = false;
    if (tid < NK_) {
        const float* lab = labels + ((size_t)b * NK_ + tid) * 5;
        float c0 = lab[0], x = lab[1], y = lab[2], w = lab[3], h = lab[4];
        bool vrow = (c0 + x + y + w + h) > 0.0f;
        float tx = x * NG_, ty = y * NG_;
        int ti = (int)tx, tj = (int)ty;

        int best = 0; float bi = -1.0f;
        #pragma unroll
        for (int n = 0; n < 9; ++n) {
            float aw = anchors[n*2]     * inv_img;
            float ah = anchors[n*2 + 1] * inv_img;
            float inter = fminf(w, aw) * fminf(h, ah);
            float uni   = w*h + aw*ah - inter;
            float iou   = inter / (uni + 1e-16f);
            if (iou > bi) { bi = iou; best = n; }
        }
        int bn = best % NA_;
        val = vrow && (best < NA_);
        if (ti < 0 || ti >= NG_ || tj < 0 || tj >= NG_) val = false;

        float w64 = w * NG_, h64 = h * NG_;
        float xc = floorf(tx) + 0.5f, yc = floorf(ty) + 0.5f;
        float lt = fmaxf(xc - (tx - w64*0.5f), 0.0f) * (1.0f/NG_);
        float tt = fmaxf(yc - (ty - h64*0.5f), 0.0f) * (1.0f/NG_);
        float rt = fmaxf(tx + w64*0.5f - xc, 0.0f) * (1.0f/NG_);
        float bt = fmaxf(ty + h64*0.5f - yc, 0.0f) * (1.0f/NG_);
        float awn = anchors[bn*2] * inv_img;
        s_tgt[tid][0] = logf(lt / awn + 1e-16f);
        s_tgt[tid][1] = logf(tt / awn + 1e-16f);
        s_tgt[tid][2] = logf(rt / awn + 1e-16f);
        s_tgt[tid][3] = logf(bt / awn + 1e-16f);

        s_cls[tid] = (int)c0;
        int code = val ? ((1 << 30) | (bn << 20) | (tj << 10) | ti) : -1;
        s_meta[tid] = make_float2(0.375f * w * h, __int_as_float(code));
        s_box[tid]  = make_float4(x - w*0.5f, y - h*0.5f, x + w*0.5f, y + h*0.5f);
    }
    // hasvalid via wave-0 ballot (lanes >= 50 contribute false)
    if (tid < 64) {
        unsigned long long bb = __ballot(val);
        if (tid == 0) s_hasvalid = (bb != 0ull) ? 1 : 0;
    }
    __syncthreads();

    // ---- decode both cells ----
    const float scale = 8.0f * inv_img;
    float tlxA, tlyA, brxA, bryA, t375A; int codeA;
    float tlxB, tlyB, brxB, bryB, t375B; int codeB;
    {
        float aw = anchors[aA*2];
        float ls = expf(r0A)*aw*0.125f, ts = expf(r1A)*aw*0.125f;
        float rs = expf(r2A)*aw*0.125f, bs = expf(r3A)*aw*0.125f;
        int i = rrA & 63, j = rrA >> 6;
        float cx = ((i + 0.5f) + (rs - ls)*0.5f) * scale;
        float cy = ((j + 0.5f) + (bs - ts)*0.5f) * scale;
        float pw = (ls + rs) * scale, ph = (ts + bs) * scale;
        tlxA = cx - pw*0.5f; tlyA = cy - ph*0.5f;
        brxA = cx + pw*0.5f; bryA = cy + ph*0.5f;
        t375A = 0.375f * (pw * ph + 1e-16f);
        codeA = (1 << 30) | (aA << 20) | (j << 10) | i;
    }
    {
        float aw = anchors[aB*2];
        float ls = expf(r0B)*aw*0.125f, ts = expf(r1B)*aw*0.125f;
        float rs = expf(r2B)*aw*0.125f, bs = expf(r3B)*aw*0.125f;
        int i = rrB & 63, j = rrB >> 6;
        float cx = ((i + 0.5f) + (rs - ls)*0.5f) * scale;
        float cy = ((j + 0.5f) + (bs - ts)*0.5f) * scale;
        float pw = (ls + rs) * scale, ph = (ts + bs) * scale;
        tlxB = cx - pw*0.5f; tlyB = cy - ph*0.5f;
        brxB = cx + pw*0.5f; bryB = cy + ph*0.5f;
        t375B = 0.375f * (pw * ph + 1e-16f);
        codeB = (1 << 30) | (aB << 20) | (j << 10) | i;
    }

    // ---- fused label loop: each LDS read feeds both cells ----
    bool ignA = false, ignB = false;
    int  kmA = -1, kmB = -1;
    #pragma unroll 5
    for (int k = 0; k < NK_; ++k) {
        float4 bx = s_box[k];
        float2 mt = s_meta[k];
        int    ck = __float_as_int(mt.y);
        {
            float iw = fminf(brxA, bx.z) - fmaxf(tlxA, bx.x);
            float ih = fminf(bryA, bx.w) - fmaxf(tlyA, bx.y);
            float inter = fmaxf(iw, 0.0f) * fmaxf(ih, 0.0f);
            ignA |= inter > (t375A + mt.x);     // iou > 0.6, div-free
            if (ck == codeA) kmA = k;
        }
        {
            float iw = fminf(brxB, bx.z) - fmaxf(tlxB, bx.x);
            float ih = fminf(bryB, bx.w) - fmaxf(tlyB, bx.y);
            float inter = fmaxf(iw, 0.0f) * fmaxf(ih, 0.0f);
            ignB |= inter > (t375B + mt.x);
            if (ck == codeB) kmB = k;
        }
    }

    float lsum = 0.0f;

    auto wave_cls = [&](int cid, bool gt, unsigned long long m0, unsigned long long m1) -> float {
        float acc = 0.0f;
        unsigned long long g = __ballot(gt);
        while (g) {
            int L = (int)__ffsll(g) - 1;
            g &= g - 1;
            int ccid = __shfl(cid, L);
            unsigned lo0 = (unsigned)__shfl((int)(unsigned)(m0 & 0xffffffffu), L);
            unsigned hi0 = (unsigned)__shfl((int)(unsigned)(m0 >> 32), L);
            unsigned lo1 = (unsigned)__shfl((int)(unsigned)(m1 & 0xffffffffu), L);
            unsigned long long mm0 = ((unsigned long long)hi0 << 32) | lo0;
            int aa = ccid >> 12, rc = ccid & 4095;
            const float* clp = raw + (((size_t)(b*NA_ + aa) * NCH_ + 5) << 12) + rc;
            float x = clp[(size_t)lane << 12];
            acc += ((mm0 >> lane) & 1ull) ? softplusf_(-x) : softplusf_(x);
            if (lane < NCLS_ - 64) {
                float y = clp[(size_t)(lane + 64) << 12];
                acc += ((lo1 >> lane) & 1u) ? softplusf_(-y) : softplusf_(y);
            }
        }
        return acc;
    };

    // ---- cell A epilogue ----
    {
        bool gt = (kmA >= 0);
        bool cm = (s_hasvalid ? !ignA : true) || gt;
        if (cm) lsum += gt ? softplusf_(-cfA) : softplusf_(cfA);
        unsigned long long m0 = 0ull, m1 = 0ull;
        if (gt) {
            float d0 = r0A - s_tgt[kmA][0], d1 = r1A - s_tgt[kmA][1];
            float d2 = r2A - s_tgt[kmA][2], d3 = r3A - s_tgt[kmA][3];
            lsum += d0*d0 + d1*d1 + d2*d2 + d3*d3;
            for (int k = 0; k < NK_; ++k) {
                if (__float_as_int(s_meta[k].y) == codeA) {
                    int tc = s_cls[k];
                    if ((unsigned)tc < 64u) m0 |= (1ull << tc);
                    else if ((unsigned)tc < (unsigned)NCLS_) m1 |= (1ull << (tc - 64));
                }
            }
        }
        lsum += wave_cls(cA, gt, m0, m1);
    }
    // ---- cell B epilogue ----
    {
        bool gt = (kmB >= 0);
        bool cm = (s_hasvalid ? !ignB : true) || gt;
        if (cm) lsum += gt ? softplusf_(-cfB) : softplusf_(cfB);
        unsigned long long m0 = 0ull, m1 = 0ull;
        if (gt) {
            float d0 = r0B - s_tgt[kmB][0], d1 = r1B - s_tgt[kmB][1];
            float d2 = r2B - s_tgt[kmB][2], d3 = r3B - s_tgt[kmB][3];
            lsum += d0*d0 + d1*d1 + d2*d2 + d3*d3;
            for (int k = 0; k < NK_; ++k) {
                if (__float_as_int(s_meta[k].y) == codeB) {
                    int tc = s_cls[k];
                    if ((unsigned)tc < 64u) m0 |= (1ull << tc);
                    else if ((unsigned)tc < (unsigned)NCLS_) m1 |= (1ull << (tc - 64));
                }
            }
        }
        lsum += wave_cls(cB, gt, m0, m1);
    }

    // ---- block reduce ----
    #pragma unroll
    for (int off = 32; off > 0; off >>= 1) lsum += __shfl_down(lsum, off);
    if (lane == 0) s_wsum[tid >> 6] = lsum;
    __syncthreads();

    // ---- publish partial with device-scope release ----
    if (tid == 0) {
        float blocksum = s_wsum[0] + s_wsum[1] + s_wsum[2];
        atomicExch(&partials[bid], blocksum);   // device-scope, reaches coherence point
        __threadfence();
        atomicExch(&flags[bid], MAGIC_);        // release flag
    }

    // ---- block GRID-1 spin-reduces all partials and writes out ----
    if (bid == GRID_ - 1) {
        for (int s = tid; s < GRID_; s += BLOCK_) {
            while (atomicOr(&flags[s], 0u) != MAGIC_) {
                __builtin_amdgcn_s_sleep(8);
            }
        }
        __syncthreads();
        float t = 0.0f;
        for (int s = tid; s < GRID_; s += BLOCK_) {
            t += __uint_as_float(atomicOr((unsigned*)&partials[s], 0u));
        }
        #pragma unroll
        for (int off = 32; off > 0; off >>= 1) t += __shfl_down(t, off);
        __syncthreads();                 // re-use s_wsum safely
        if (lane == 0) s_wsum[tid >> 6] = t;
        __syncthreads();
        if (tid == 0) out[0] = s_wsum[0] + s_wsum[1] + s_wsum[2];
    }
}

extern "C" void kernel_launch(void* const* d_in, const int* in_sizes, int n_in,
                              void* d_out, int out_size, void* d_ws, size_t ws_size,
                              hipStream_t stream) {
    const float* raw     = (const float*)d_in[0];
    const float* labels  = (const float*)d_in[1];
    const float* anchors = (const float*)d_in[2];
    const int*   img     = (const int*)d_in[3];
    float* out = (float*)d_out;
    float*    partials = (float*)d_ws;
    unsigned* flags    = (unsigned*)((float*)d_ws + GRID_);

    fcos_loss_kernel<<<dim3(GRID_), dim3(BLOCK_), 0, stream>>>(
        raw, labels, anchors, img, out, partials, flags);
}

// Round 5
// 17.348 us; speedup vs baseline: 3.5530x; 1.2303x over previous
//
#include <hip/hip_runtime.h>

// FCOSLayer_22840636080477 — fused YOLO-style loss on MI355X (round 5).
// vs R4: valid-label compaction (hot loop 50 -> ~27 iters), match via LDS
// scatter (gt known before IoU loop), 2-slot class-logit prefetch hides
// scattered-load latency under the IoU loop, float2 channel loads.

constexpr int NA_   = 3;
constexpr int NG_   = 64;
constexpr int NCLS_ = 80;
constexpr int NK_   = 50;
constexpr int NCH_  = 85;    // 5 + NCLS
constexpr int BLOCK_ = 192;  // 3 waves
constexpr int GRID_  = 512;
constexpr int CPB_   = 384;  // cells per block (2 per thread, adjacent)
constexpr unsigned MAGIC_ = 0x5A17C0DEu;

__device__ __forceinline__ float softplusf_(float x) {
    return fmaxf(x, 0.0f) + log1pf(expf(-fabsf(x)));
}

__global__ __launch_bounds__(BLOCK_) void fcos_loss_kernel(
    const float* __restrict__ raw,
    const float* __restrict__ labels,
    const float* __restrict__ anchors,
    const int*   __restrict__ img_size_p,
    float*       __restrict__ out,
    float*       __restrict__ partials,
    unsigned*    __restrict__ flags)
{
    __shared__ float4 s_box[NK_];        // compacted valid_row boxes (corners)
    __shared__ float  s_a375[NK_];       // compacted 0.375*area
    __shared__ float  s_tgt[NK_][4];     // per-ORIGINAL-label ltrb target
    __shared__ int    s_cls[NK_];        // per-ORIGINAL-label class
    __shared__ int    s_cm[CPB_];        // local cell -> label idx (or -1)
    __shared__ int    s_nvr;             // count of valid_row labels
    __shared__ int    s_hasvalid;
    __shared__ float  s_wsum[BLOCK_ / 64];

    const int tid  = threadIdx.x;
    const int lane = tid & 63;
    const int bid  = blockIdx.x;
    const int b    = bid >> 5;                  // 32 blocks per batch
    const int base = (bid & 31) * CPB_;
    const float inv_img = 1.0f / (float)img_size_p[0];

    // ---- issue channel loads first (float2 = both cells of this thread) ----
    const int cid0 = base + 2 * tid;            // even; pair never straddles a/row
    const int a0 = cid0 >> 12, rr = cid0 & 4095;
    const float* cbase = raw + (((size_t)(b * NA_ + a0) * NCH_) << 12) + rr;
    const float2 ch0 = *(const float2*)(cbase);
    const float2 ch1 = *(const float2*)(cbase + 4096);
    const float2 ch2 = *(const float2*)(cbase + 2 * 4096);
    const float2 ch3 = *(const float2*)(cbase + 3 * 4096);
    const float2 ch4 = *(const float2*)(cbase + 4 * 4096);

    // ---- wave 0: init s_cm, label preproc with compaction + scatter ----
    if (tid < 64) {
        #pragma unroll
        for (int q = 0; q < CPB_ / 64; ++q) s_cm[lane + 64 * q] = -1;

        bool vrow = false, val = false;
        float c0l = 0, x = 0, y = 0, w = 0, h = 0;
        int ti = 0, tj = 0, bn = 0;
        if (lane < NK_) {
            const float* lab = labels + ((size_t)b * NK_ + lane) * 5;
            c0l = lab[0]; x = lab[1]; y = lab[2]; w = lab[3]; h = lab[4];
            vrow = (c0l + x + y + w + h) > 0.0f;
            float tx = x * NG_, ty = y * NG_;
            ti = (int)tx; tj = (int)ty;

            int best = 0; float bi = -1.0f;
            #pragma unroll
            for (int n = 0; n < 9; ++n) {
                float aw = anchors[n*2]     * inv_img;
                float ah = anchors[n*2 + 1] * inv_img;
                float inter = fminf(w, aw) * fminf(h, ah);
                float uni   = w*h + aw*ah - inter;
                float iou   = inter / (uni + 1e-16f);
                if (iou > bi) { bi = iou; best = n; }
            }
            bn  = best % NA_;
            val = vrow && (best < NA_) &&
                  ti >= 0 && ti < NG_ && tj >= 0 && tj < NG_;

            if (val) {
                float tx2 = tx, ty2 = ty;
                float w64 = w * NG_, h64 = h * NG_;
                float xc = floorf(tx2) + 0.5f, yc = floorf(ty2) + 0.5f;
                float lt = fmaxf(xc - (tx2 - w64*0.5f), 0.0f) * (1.0f/NG_);
                float tt = fmaxf(yc - (ty2 - h64*0.5f), 0.0f) * (1.0f/NG_);
                float rt = fmaxf(tx2 + w64*0.5f - xc, 0.0f) * (1.0f/NG_);
                float bt = fmaxf(ty2 + h64*0.5f - yc, 0.0f) * (1.0f/NG_);
                float awn = anchors[bn*2] * inv_img;
                s_tgt[lane][0] = logf(lt / awn + 1e-16f);
                s_tgt[lane][1] = logf(tt / awn + 1e-16f);
                s_tgt[lane][2] = logf(rt / awn + 1e-16f);
                s_tgt[lane][3] = logf(bt / awn + 1e-16f);
                s_cls[lane] = (int)c0l;
            }
        }
        unsigned long long bbv = __ballot(vrow);
        unsigned long long bba = __ballot(val);
        if (lane < NK_ && vrow) {
            int pos = (int)__popcll(bbv & ((1ull << lane) - 1ull));
            s_box[pos]  = make_float4(x - w*0.5f, y - h*0.5f, x + w*0.5f, y + h*0.5f);
            s_a375[pos] = 0.375f * w * h;
        }
        if (lane < NK_ && val) {
            int tcid = (bn << 12) | (tj << 6) | ti;
            unsigned loc = (unsigned)(tcid - base);
            if (loc < (unsigned)CPB_) s_cm[loc] = lane;
        }
        if (lane == 0) {
            s_nvr      = (int)__popcll(bbv);
            s_hasvalid = (bba != 0ull) ? 1 : 0;
        }
    }
    __syncthreads();

    // ---- decode both cells ----
    const float scale = 8.0f * inv_img;
    const float aw0 = anchors[a0 * 2];
    const int i0 = rr & 63, j0 = rr >> 6;

    float tlx0, tly0, brx0, bry0, t3750;
    float tlx1, tly1, brx1, bry1, t3751;
    {
        float ls = expf(ch0.x)*aw0*0.125f, ts = expf(ch1.x)*aw0*0.125f;
        float rs = expf(ch2.x)*aw0*0.125f, bs = expf(ch3.x)*aw0*0.125f;
        float cx = ((i0 + 0.5f) + (rs - ls)*0.5f) * scale;
        float cy = ((j0 + 0.5f) + (bs - ts)*0.5f) * scale;
        float pw = (ls + rs) * scale, ph = (ts + bs) * scale;
        tlx0 = cx - pw*0.5f; tly0 = cy - ph*0.5f;
        brx0 = cx + pw*0.5f; bry0 = cy + ph*0.5f;
        t3750 = 0.375f * (pw * ph + 1e-16f);
    }
    {
        float ls = expf(ch0.y)*aw0*0.125f, ts = expf(ch1.y)*aw0*0.125f;
        float rs = expf(ch2.y)*aw0*0.125f, bs = expf(ch3.y)*aw0*0.125f;
        float cx = ((i0 + 1.5f) + (rs - ls)*0.5f) * scale;
        float cy = ((j0 + 0.5f) + (bs - ts)*0.5f) * scale;
        float pw = (ls + rs) * scale, ph = (ts + bs) * scale;
        tlx1 = cx - pw*0.5f; tly1 = cy - ph*0.5f;
        brx1 = cx + pw*0.5f; bry1 = cy + ph*0.5f;
        t3751 = 0.375f * (pw * ph + 1e-16f);
    }

    // ---- match via LDS (known BEFORE the IoU loop) ----
    const int km0 = s_cm[2*tid], km1 = s_cm[2*tid + 1];
    const bool gt0 = km0 >= 0, gt1 = km1 >= 0;
    const int cls0 = gt0 ? s_cls[km0] : 0;
    const int cls1 = gt1 ? s_cls[km1] : 0;

    float lsum = 0.0f;
    if (gt0) {
        float d0 = ch0.x - s_tgt[km0][0], d1 = ch1.x - s_tgt[km0][1];
        float d2 = ch2.x - s_tgt[km0][2], d3 = ch3.x - s_tgt[km0][3];
        lsum += d0*d0 + d1*d1 + d2*d2 + d3*d3;
    }
    if (gt1) {
        float d0 = ch0.y - s_tgt[km1][0], d1 = ch1.y - s_tgt[km1][1];
        float d2 = ch2.y - s_tgt[km1][2], d3 = ch3.y - s_tgt[km1][3];
        lsum += d0*d0 + d1*d1 + d2*d2 + d3*d3;
    }

    // ---- 2-slot class-logit prefetch (loads in flight across IoU loop) ----
    unsigned long long gA = __ballot(gt0), gB = __ballot(gt1);
    int scid0 = 0, scls0 = 0, scid1 = 0, scls1 = 0;
    bool h0 = false, h1 = false;
    float px0 = 0, py0 = 0, px1 = 0, py1 = 0;

    if (gA) { int L = (int)__ffsll(gA) - 1; gA &= gA - 1;
              scid0 = __shfl(cid0, L);     scls0 = __shfl(cls0, L); h0 = true; }
    else if (gB) { int L = (int)__ffsll(gB) - 1; gB &= gB - 1;
              scid0 = __shfl(cid0 + 1, L); scls0 = __shfl(cls1, L); h0 = true; }
    if (h0) {
        int aa = scid0 >> 12, rc = scid0 & 4095;
        const float* clp = raw + (((size_t)(b*NA_ + aa) * NCH_ + 5) << 12) + rc;
        px0 = clp[(size_t)lane << 12];
        py0 = (lane < NCLS_ - 64) ? clp[(size_t)(lane + 64) << 12] : 0.0f;
    }
    if (gA) { int L = (int)__ffsll(gA) - 1; gA &= gA - 1;
              scid1 = __shfl(cid0, L);     scls1 = __shfl(cls0, L); h1 = true; }
    else if (gB) { int L = (int)__ffsll(gB) - 1; gB &= gB - 1;
              scid1 = __shfl(cid0 + 1, L); scls1 = __shfl(cls1, L); h1 = true; }
    if (h1) {
        int aa = scid1 >> 12, rc = scid1 & 4095;
        const float* clp = raw + (((size_t)(b*NA_ + aa) * NCH_ + 5) << 12) + rc;
        px1 = clp[(size_t)lane << 12];
        py1 = (lane < NCLS_ - 64) ? clp[(size_t)(lane + 64) << 12] : 0.0f;
    }

    // ---- IoU ignore loop over COMPACTED valid labels ----
    const int nv = s_nvr;
    bool ign0 = false, ign1 = false;
    #pragma unroll 2
    for (int k = 0; k < nv; ++k) {
        float4 bx = s_box[k];
        float  ak = s_a375[k];
        {
            float iw = fminf(brx0, bx.z) - fmaxf(tlx0, bx.x);
            float ih = fminf(bry0, bx.w) - fmaxf(tly0, bx.y);
            float inter = fmaxf(iw, 0.0f) * fmaxf(ih, 0.0f);
            ign0 |= inter > (t3750 + ak);
        }
        {
            float iw = fminf(brx1, bx.z) - fmaxf(tlx1, bx.x);
            float ih = fminf(bry1, bx.w) - fmaxf(tly1, bx.y);
            float inter = fmaxf(iw, 0.0f) * fmaxf(ih, 0.0f);
            ign1 |= inter > (t3751 + ak);
        }
    }

    // ---- conf BCE ----
    const int hv = s_hasvalid;
    if ((hv ? !ign0 : true) || gt0) lsum += gt0 ? softplusf_(-ch4.x) : softplusf_(ch4.x);
    if ((hv ? !ign1 : true) || gt1) lsum += gt1 ? softplusf_(-ch4.y) : softplusf_(ch4.y);

    // ---- consume prefetched class BCE ----
    if (h0) {
        lsum += (lane == scls0) ? softplusf_(-px0) : softplusf_(px0);
        if (lane < NCLS_ - 64)
            lsum += (lane + 64 == scls0) ? softplusf_(-py0) : softplusf_(py0);
    }
    if (h1) {
        lsum += (lane == scls1) ? softplusf_(-px1) : softplusf_(px1);
        if (lane < NCLS_ - 64)
            lsum += (lane + 64 == scls1) ? softplusf_(-py1) : softplusf_(py1);
    }
    // rare: >2 gt cells in wave
    while (gA) {
        int L = (int)__ffsll(gA) - 1; gA &= gA - 1;
        int scid = __shfl(cid0, L), scls = __shfl(cls0, L);
        int aa = scid >> 12, rc = scid & 4095;
        const float* clp = raw + (((size_t)(b*NA_ + aa) * NCH_ + 5) << 12) + rc;
        float x = clp[(size_t)lane << 12];
        lsum += (lane == scls) ? softplusf_(-x) : softplusf_(x);
        if (lane < NCLS_ - 64) {
            float y = clp[(size_t)(lane + 64) << 12];
            lsum += (lane + 64 == scls) ? softplusf_(-y) : softplusf_(y);
        }
    }
    while (gB) {
        int L = (int)__ffsll(gB) - 1; gB &= gB - 1;
        int scid = __shfl(cid0 + 1, L), scls = __shfl(cls1, L);
        int aa = scid >> 12, rc = scid & 4095;
        const float* clp = raw + (((size_t)(b*NA_ + aa) * NCH_ + 5) << 12) + rc;
        float x = clp[(size_t)lane << 12];
        lsum += (lane == scls) ? softplusf_(-x) : softplusf_(x);
        if (lane < NCLS_ - 64) {
            float y = clp[(size_t)(lane + 64) << 12];
            lsum += (lane + 64 == scls) ? softplusf_(-y) : softplusf_(y);
        }
    }

    // ---- block reduce ----
    #pragma unroll
    for (int off = 32; off > 0; off >>= 1) lsum += __shfl_down(lsum, off);
    if (lane == 0) s_wsum[tid >> 6] = lsum;
    __syncthreads();

    // ---- publish partial with device-scope release ----
    if (tid == 0) {
        float blocksum = s_wsum[0] + s_wsum[1] + s_wsum[2];
        atomicExch(&partials[bid], blocksum);
        __threadfence();
        atomicExch(&flags[bid], MAGIC_);
    }

    // ---- block GRID-1 spin-reduces all partials and writes out ----
    if (bid == GRID_ - 1) {
        for (int s = tid; s < GRID_; s += BLOCK_) {
            while (atomicOr(&flags[s], 0u) != MAGIC_) {
                __builtin_amdgcn_s_sleep(8);
            }
        }
        __syncthreads();
        float t = 0.0f;
        for (int s = tid; s < GRID_; s += BLOCK_) {
            t += __uint_as_float(atomicOr((unsigned*)&partials[s], 0u));
        }
        #pragma unroll
        for (int off = 32; off > 0; off >>= 1) t += __shfl_down(t, off);
        __syncthreads();
        if (lane == 0) s_wsum[tid >> 6] = t;
        __syncthreads();
        if (tid == 0) out[0] = s_wsum[0] + s_wsum[1] + s_wsum[2];
    }
}

extern "C" void kernel_launch(void* const* d_in, const int* in_sizes, int n_in,
                              void* d_out, int out_size, void* d_ws, size_t ws_size,
                              hipStream_t stream) {
    const float* raw     = (const float*)d_in[0];
    const float* labels  = (const float*)d_in[1];
    const float* anchors = (const float*)d_in[2];
    const int*   img     = (const int*)d_in[3];
    float* out = (float*)d_out;
    float*    partials = (float*)d_ws;
    unsigned* flags    = (unsigned*)((float*)d_ws + GRID_);

    fcos_loss_kernel<<<dim3(GRID_), dim3(BLOCK_), 0, stream>>>(
        raw, labels, anchors, img, out, partials, flags);
}

// Round 6
// 14.347 us; speedup vs baseline: 4.2962x; 1.2092x over previous
//
#include <hip/hip_runtime.h>

// FCOSLayer_22840636080477 — fused YOLO-style loss on MI355X (round 6).
// vs R5: packed {MAGIC,value} 64-bit single-atomic publish (no threadfence,
// half the tail atomics), decode moved before the barrier (overlaps wave-0
// label preprocessing), label loads issued ahead of channel loads.

constexpr int NA_   = 3;
constexpr int NG_   = 64;
constexpr int NCLS_ = 80;
constexpr int NK_   = 50;
constexpr int NCH_  = 85;    // 5 + NCLS
constexpr int BLOCK_ = 192;  // 3 waves
constexpr int GRID_  = 512;  // 2 blocks/CU exactly
constexpr int CPB_   = 384;  // cells per block (2 per thread, adjacent)
constexpr unsigned MAGIC_ = 0x5A17C0DEu;

__device__ __forceinline__ float softplusf_(float x) {
    return fmaxf(x, 0.0f) + log1pf(expf(-fabsf(x)));
}

__global__ __launch_bounds__(BLOCK_) void fcos_loss_kernel(
    const float* __restrict__ raw,
    const float* __restrict__ labels,
    const float* __restrict__ anchors,
    const int*   __restrict__ img_size_p,
    float*       __restrict__ out,
    unsigned long long* __restrict__ slots)
{
    __shared__ float4 s_box[NK_];        // compacted valid_row boxes (corners)
    __shared__ float  s_a375[NK_];       // compacted 0.375*area
    __shared__ float  s_tgt[NK_][4];     // per-ORIGINAL-label ltrb target
    __shared__ int    s_cls[NK_];        // per-ORIGINAL-label class
    __shared__ int    s_cm[CPB_];        // local cell -> label idx (or -1)
    __shared__ int    s_nvr;             // count of valid_row labels
    __shared__ int    s_hasvalid;
    __shared__ float  s_wsum[BLOCK_ / 64];

    const int tid  = threadIdx.x;
    const int lane = tid & 63;
    const int bid  = blockIdx.x;
    const int b    = bid >> 5;                  // 32 blocks per batch
    const int base = (bid & 31) * CPB_;
    const float inv_img = 1.0f / (float)img_size_p[0];

    // ---- wave-0 label loads FIRST (so preproc's vmcnt wait leaves channel
    //      loads in flight), then everyone's channel loads ----
    float c0l = 0, lx = 0, ly = 0, lw = 0, lh = 0;
    if (tid < NK_) {
        const float* lab = labels + ((size_t)b * NK_ + tid) * 5;
        c0l = lab[0]; lx = lab[1]; ly = lab[2]; lw = lab[3]; lh = lab[4];
    }

    const int cid0 = base + 2 * tid;            // even; pair never straddles a/row
    const int a0 = cid0 >> 12, rr = cid0 & 4095;
    const float* cbase = raw + (((size_t)(b * NA_ + a0) * NCH_) << 12) + rr;
    const float2 ch0 = *(const float2*)(cbase);
    const float2 ch1 = *(const float2*)(cbase + 4096);
    const float2 ch2 = *(const float2*)(cbase + 2 * 4096);
    const float2 ch3 = *(const float2*)(cbase + 3 * 4096);
    const float2 ch4 = *(const float2*)(cbase + 4 * 4096);

    // ---- wave 0: init s_cm, label preproc with compaction + scatter ----
    if (tid < 64) {
        #pragma unroll
        for (int q = 0; q < CPB_ / 64; ++q) s_cm[lane + 64 * q] = -1;

        bool vrow = false, val = false;
        int ti = 0, tj = 0, bn = 0;
        if (lane < NK_) {
            vrow = (c0l + lx + ly + lw + lh) > 0.0f;
            float tx = lx * NG_, ty = ly * NG_;
            ti = (int)tx; tj = (int)ty;

            int best = 0; float bi = -1.0f;
            #pragma unroll
            for (int n = 0; n < 9; ++n) {
                float aw = anchors[n*2]     * inv_img;
                float ah = anchors[n*2 + 1] * inv_img;
                float inter = fminf(lw, aw) * fminf(lh, ah);
                float uni   = lw*lh + aw*ah - inter;
                float iou   = inter / (uni + 1e-16f);
                if (iou > bi) { bi = iou; best = n; }
            }
            bn  = best % NA_;
            val = vrow && (best < NA_) &&
                  ti >= 0 && ti < NG_ && tj >= 0 && tj < NG_;

            if (val) {
                float tx2 = tx, ty2 = ty;
                float w64 = lw * NG_, h64 = lh * NG_;
                float xc = floorf(tx2) + 0.5f, yc = floorf(ty2) + 0.5f;
                float lt = fmaxf(xc - (tx2 - w64*0.5f), 0.0f) * (1.0f/NG_);
                float tt = fmaxf(yc - (ty2 - h64*0.5f), 0.0f) * (1.0f/NG_);
                float rt = fmaxf(tx2 + w64*0.5f - xc, 0.0f) * (1.0f/NG_);
                float bt = fmaxf(ty2 + h64*0.5f - yc, 0.0f) * (1.0f/NG_);
                float awn = anchors[bn*2] * inv_img;
                s_tgt[lane][0] = logf(lt / awn + 1e-16f);
                s_tgt[lane][1] = logf(tt / awn + 1e-16f);
                s_tgt[lane][2] = logf(rt / awn + 1e-16f);
                s_tgt[lane][3] = logf(bt / awn + 1e-16f);
                s_cls[lane] = (int)c0l;
            }
        }
        unsigned long long bbv = __ballot(vrow);
        unsigned long long bba = __ballot(val);
        if (lane < NK_ && vrow) {
            int pos = (int)__popcll(bbv & ((1ull << lane) - 1ull));
            s_box[pos]  = make_float4(lx - lw*0.5f, ly - lh*0.5f,
                                      lx + lw*0.5f, ly + lh*0.5f);
            s_a375[pos] = 0.375f * lw * lh;
        }
        if (lane < NK_ && val) {
            int tcid = (bn << 12) | (tj << 6) | ti;
            unsigned loc = (unsigned)(tcid - base);
            if (loc < (unsigned)CPB_) s_cm[loc] = lane;
        }
        if (lane == 0) {
            s_nvr      = (int)__popcll(bbv);
            s_hasvalid = (bba != 0ull) ? 1 : 0;
        }
    }

    // ---- decode both cells BEFORE the barrier (waves 1-2 overlap preproc) ----
    const float scale = 8.0f * inv_img;
    const float aw0 = anchors[a0 * 2];
    const int i0 = rr & 63, j0 = rr >> 6;

    float tlx0, tly0, brx0, bry0, t3750;
    float tlx1, tly1, brx1, bry1, t3751;
    {
        float ls = expf(ch0.x)*aw0*0.125f, ts = expf(ch1.x)*aw0*0.125f;
        float rs = expf(ch2.x)*aw0*0.125f, bs = expf(ch3.x)*aw0*0.125f;
        float cx = ((i0 + 0.5f) + (rs - ls)*0.5f) * scale;
        float cy = ((j0 + 0.5f) + (bs - ts)*0.5f) * scale;
        float pw = (ls + rs) * scale, ph = (ts + bs) * scale;
        tlx0 = cx - pw*0.5f; tly0 = cy - ph*0.5f;
        brx0 = cx + pw*0.5f; bry0 = cy + ph*0.5f;
        t3750 = 0.375f * (pw * ph + 1e-16f);
    }
    {
        float ls = expf(ch0.y)*aw0*0.125f, ts = expf(ch1.y)*aw0*0.125f;
        float rs = expf(ch2.y)*aw0*0.125f, bs = expf(ch3.y)*aw0*0.125f;
        float cx = ((i0 + 1.5f) + (rs - ls)*0.5f) * scale;
        float cy = ((j0 + 0.5f) + (bs - ts)*0.5f) * scale;
        float pw = (ls + rs) * scale, ph = (ts + bs) * scale;
        tlx1 = cx - pw*0.5f; tly1 = cy - ph*0.5f;
        brx1 = cx + pw*0.5f; bry1 = cy + ph*0.5f;
        t3751 = 0.375f * (pw * ph + 1e-16f);
    }
    __syncthreads();

    // ---- match via LDS (known BEFORE the IoU loop) ----
    const int km0 = s_cm[2*tid], km1 = s_cm[2*tid + 1];
    const bool gt0 = km0 >= 0, gt1 = km1 >= 0;
    const int cls0 = gt0 ? s_cls[km0] : 0;
    const int cls1 = gt1 ? s_cls[km1] : 0;

    float lsum = 0.0f;
    if (gt0) {
        float d0 = ch0.x - s_tgt[km0][0], d1 = ch1.x - s_tgt[km0][1];
        float d2 = ch2.x - s_tgt[km0][2], d3 = ch3.x - s_tgt[km0][3];
        lsum += d0*d0 + d1*d1 + d2*d2 + d3*d3;
    }
    if (gt1) {
        float d0 = ch0.y - s_tgt[km1][0], d1 = ch1.y - s_tgt[km1][1];
        float d2 = ch2.y - s_tgt[km1][2], d3 = ch3.y - s_tgt[km1][3];
        lsum += d0*d0 + d1*d1 + d2*d2 + d3*d3;
    }

    // ---- 2-slot class-logit prefetch (loads in flight across IoU loop) ----
    unsigned long long gA = __ballot(gt0), gB = __ballot(gt1);
    int scid0 = 0, scls0 = 0, scid1 = 0, scls1 = 0;
    bool h0 = false, h1 = false;
    float px0 = 0, py0 = 0, px1 = 0, py1 = 0;

    if (gA) { int L = (int)__ffsll(gA) - 1; gA &= gA - 1;
              scid0 = __shfl(cid0, L);     scls0 = __shfl(cls0, L); h0 = true; }
    else if (gB) { int L = (int)__ffsll(gB) - 1; gB &= gB - 1;
              scid0 = __shfl(cid0 + 1, L); scls0 = __shfl(cls1, L); h0 = true; }
    if (h0) {
        int aa = scid0 >> 12, rc = scid0 & 4095;
        const float* clp = raw + (((size_t)(b*NA_ + aa) * NCH_ + 5) << 12) + rc;
        px0 = clp[(size_t)lane << 12];
        py0 = (lane < NCLS_ - 64) ? clp[(size_t)(lane + 64) << 12] : 0.0f;
    }
    if (gA) { int L = (int)__ffsll(gA) - 1; gA &= gA - 1;
              scid1 = __shfl(cid0, L);     scls1 = __shfl(cls0, L); h1 = true; }
    else if (gB) { int L = (int)__ffsll(gB) - 1; gB &= gB - 1;
              scid1 = __shfl(cid0 + 1, L); scls1 = __shfl(cls1, L); h1 = true; }
    if (h1) {
        int aa = scid1 >> 12, rc = scid1 & 4095;
        const float* clp = raw + (((size_t)(b*NA_ + aa) * NCH_ + 5) << 12) + rc;
        px1 = clp[(size_t)lane << 12];
        py1 = (lane < NCLS_ - 64) ? clp[(size_t)(lane + 64) << 12] : 0.0f;
    }

    // ---- IoU ignore loop over COMPACTED valid labels ----
    const int nv = s_nvr;
    bool ign0 = false, ign1 = false;
    #pragma unroll 2
    for (int k = 0; k < nv; ++k) {
        float4 bx = s_box[k];
        float  ak = s_a375[k];
        {
            float iw = fminf(brx0, bx.z) - fmaxf(tlx0, bx.x);
            float ih = fminf(bry0, bx.w) - fmaxf(tly0, bx.y);
            float inter = fmaxf(iw, 0.0f) * fmaxf(ih, 0.0f);
            ign0 |= inter > (t3750 + ak);
        }
        {
            float iw = fminf(brx1, bx.z) - fmaxf(tlx1, bx.x);
            float ih = fminf(bry1, bx.w) - fmaxf(tly1, bx.y);
            float inter = fmaxf(iw, 0.0f) * fmaxf(ih, 0.0f);
            ign1 |= inter > (t3751 + ak);
        }
    }

    // ---- conf BCE ----
    const int hv = s_hasvalid;
    if ((hv ? !ign0 : true) || gt0) lsum += gt0 ? softplusf_(-ch4.x) : softplusf_(ch4.x);
    if ((hv ? !ign1 : true) || gt1) lsum += gt1 ? softplusf_(-ch4.y) : softplusf_(ch4.y);

    // ---- consume prefetched class BCE ----
    if (h0) {
        lsum += (lane == scls0) ? softplusf_(-px0) : softplusf_(px0);
        if (lane < NCLS_ - 64)
            lsum += (lane + 64 == scls0) ? softplusf_(-py0) : softplusf_(py0);
    }
    if (h1) {
        lsum += (lane == scls1) ? softplusf_(-px1) : softplusf_(px1);
        if (lane < NCLS_ - 64)
            lsum += (lane + 64 == scls1) ? softplusf_(-py1) : softplusf_(py1);
    }
    // rare: >2 gt cells in wave
    while (gA) {
        int L = (int)__ffsll(gA) - 1; gA &= gA - 1;
        int scid = __shfl(cid0, L), scls = __shfl(cls0, L);
        int aa = scid >> 12, rc = scid & 4095;
        const float* clp = raw + (((size_t)(b*NA_ + aa) * NCH_ + 5) << 12) + rc;
        float x = clp[(size_t)lane << 12];
        lsum += (lane == scls) ? softplusf_(-x) : softplusf_(x);
        if (lane < NCLS_ - 64) {
            float y = clp[(size_t)(lane + 64) << 12];
            lsum += (lane + 64 == scls) ? softplusf_(-y) : softplusf_(y);
        }
    }
    while (gB) {
        int L = (int)__ffsll(gB) - 1; gB &= gB - 1;
        int scid = __shfl(cid0 + 1, L), scls = __shfl(cls1, L);
        int aa = scid >> 12, rc = scid & 4095;
        const float* clp = raw + (((size_t)(b*NA_ + aa) * NCH_ + 5) << 12) + rc;
        float x = clp[(size_t)lane << 12];
        lsum += (lane == scls) ? softplusf_(-x) : softplusf_(x);
        if (lane < NCLS_ - 64) {
            float y = clp[(size_t)(lane + 64) << 12];
            lsum += (lane + 64 == scls) ? softplusf_(-y) : softplusf_(y);
        }
    }

    // ---- block reduce ----
    #pragma unroll
    for (int off = 32; off > 0; off >>= 1) lsum += __shfl_down(lsum, off);
    if (lane == 0) s_wsum[tid >> 6] = lsum;
    __syncthreads();

    // ---- single-atomic packed publish: {MAGIC | bits(partial)} ----
    if (tid == 0) {
        float blocksum = s_wsum[0] + s_wsum[1] + s_wsum[2];
        unsigned long long packed =
            ((unsigned long long)MAGIC_ << 32) |
            (unsigned long long)__float_as_uint(blocksum);
        atomicExch(&slots[bid], packed);
    }

    // ---- block GRID-1 spin-reduces all packed slots and writes out ----
    if (bid == GRID_ - 1) {
        float t = 0.0f;
        for (int s = tid; s < GRID_; s += BLOCK_) {
            unsigned long long v = atomicOr(&slots[s], 0ull);
            while ((unsigned)(v >> 32) != MAGIC_) {
                __builtin_amdgcn_s_sleep(8);
                v = atomicOr(&slots[s], 0ull);
            }
            t += __uint_as_float((unsigned)v);
        }
        #pragma unroll
        for (int off = 32; off > 0; off >>= 1) t += __shfl_down(t, off);
        __syncthreads();
        if (lane == 0) s_wsum[tid >> 6] = t;
        __syncthreads();
        if (tid == 0) out[0] = s_wsum[0] + s_wsum[1] + s_wsum[2];
    }
}

extern "C" void kernel_launch(void* const* d_in, const int* in_sizes, int n_in,
                              void* d_out, int out_size, void* d_ws, size_t ws_size,
                              hipStream_t stream) {
    const float* raw     = (const float*)d_in[0];
    const float* labels  = (const float*)d_in[1];
    const float* anchors = (const float*)d_in[2];
    const int*   img     = (const int*)d_in[3];
    float* out = (float*)d_out;
    unsigned long long* slots = (unsigned long long*)d_ws;

    fcos_loss_kernel<<<dim3(GRID_), dim3(BLOCK_), 0, stream>>>(
        raw, labels, anchors, img, out, slots);
}